// Round 4
// baseline (1294.325 us; speedup 1.0000x reference)
//
#include <hip/hip_runtime.h>
#include <math.h>

#define KF 4752          // feature dim: 96 + 96 + 4560
#define G4 384           // 4*C1 gates
#define NPAIR 4560
#define EPSBN 1e-5f

// Segment geometry for T=300, N_SEG=50 (derived exactly, incl. banker's
// rounding of linspace at i=25: 150.5 -> 150).
__device__ __forceinline__ int seg_start(int s){ return (s<=24)? 6*s : 149 + 6*(s-25); }
__device__ __forceinline__ int seg_len(int s){ return (s==24)?5:6; }

// ---------------- precompute: Geff[m][o][v][c*25+u], Beff[m][o][v], pairs ----
__global__ void kGeff(const float* bn_g, const float* bn_v,
                      const float* Ap, const float* Ar, const float* Wg,
                      const float* bn2_g, const float* bn2_v, float* geff){
  int idx = blockIdx.x*256 + threadIdx.x;
  if (idx >= 2*96*25*75) return;
  int cu = idx % 75; int rest = idx/75;
  int v = rest % 25; rest /= 25;
  int o = rest % 96; int m = rest / 96;
  int c = cu/25, u = cu%25;
  int ch = (m*25+u)*3 + c;
  float s1 = bn_g[ch] / sqrtf(bn_v[ch] + EPSBN);
  float s2 = bn2_g[o] / sqrtf(bn2_v[o] + EPSBN);
  float acc = 0.f;
  for (int k=0;k<13;k++){
    float a = Ap[(k*25+v)*25+u] + Ar[(k*25+v)*25+u];
    acc += Wg[o*39 + k*3 + c] * a;
  }
  geff[idx] = acc * s1 * s2;
}

__global__ void kBeff(const float* bn_g,const float* bn_b,const float* bn_m,const float* bn_v,
                      const float* Ap,const float* Ar,const float* Wg,const float* bg,
                      const float* bn2_g,const float* bn2_b,const float* bn2_m,const float* bn2_v,
                      float* beff){
  int idx = blockIdx.x*256+threadIdx.x;
  if (idx >= 2*96*25) return;
  int v = idx%25; int rest = idx/25; int o = rest%96; int m = rest/96;
  float acc = 0.f;
  for (int k=0;k<13;k++) for(int c=0;c<3;c++){
    float w = Wg[o*39+k*3+c];
    for (int u=0;u<25;u++){
      int ch = (m*25+u)*3+c;
      float s1 = bn_g[ch]/sqrtf(bn_v[ch]+EPSBN);
      float t1 = bn_b[ch] - bn_m[ch]*s1;
      acc += w * (Ap[(k*25+v)*25+u]+Ar[(k*25+v)*25+u]) * t1;
    }
  }
  acc += bg[o];
  float s2 = bn2_g[o]/sqrtf(bn2_v[o]+EPSBN);
  beff[idx] = s2*(acc - bn2_m[o]) + bn2_b[o];
}

__global__ void kPairs(int* pairs){
  int k = blockIdx.x*256+threadIdx.x;
  if (k >= NPAIR) return;
  int i=0, rem=k;
  while (rem >= 95 - i){ rem -= (95 - i); i++; }
  int j = i + 1 + rem;
  pairs[k] = (i<<7) | j;
}

// ---------------- p[b=nm*25+v][t][o] = relu(sum_cu Geff*x + Beff) -----------
#define TTILE 10
__global__ __launch_bounds__(256) void kP(const float* x, const float* geff, const float* beff, float* p){
  int nm = blockIdx.y;            // 0..7  (n*2+m)
  int t0 = blockIdx.x * TTILE;
  int m  = nm % 2;
  __shared__ float xs[75*TTILE];
  int tid = threadIdx.x;
  for (int li = tid; li < 75*TTILE; li += 256){
    int u = li % 25; int rest = li/25; int tt = rest % TTILE; int c = rest / TTILE;
    xs[(c*25+u)*TTILE + tt] = x[(((size_t)nm*3 + c)*300 + (t0+tt))*25 + u];
  }
  __syncthreads();
  for (int ow = tid; ow < 2400; ow += 256){
    int o = ow % 96, v = ow / 96;
    const float* g = geff + ((size_t)(m*96+o)*25 + v)*75;
    float b = beff[(m*96+o)*25+v];
    float acc[TTILE];
    #pragma unroll
    for (int t=0;t<TTILE;t++) acc[t] = b;
    for (int cu=0; cu<75; cu++){
      float gv = g[cu];
      #pragma unroll
      for (int t=0;t<TTILE;t++) acc[t] += gv * xs[cu*TTILE+t];
    }
    #pragma unroll
    for (int t=0;t<TTILE;t++)
      p[((size_t)(nm*25+v)*300 + t0+t)*96 + o] = fmaxf(acc[t], 0.f);
  }
}

// ---------------- feat rows: [start(96) | s1(96) | ls2(4560)] ---------------
__global__ __launch_bounds__(256) void kFeat(const float* p, const int* pairs, float* feat, int row0){
  int row = row0 + blockIdx.x;
  int b = row / 50, s = row % 50;
  int S = seg_start(s), len = seg_len(s);
  __shared__ float ps[6][96];
  __shared__ float ds[6][96];
  int tid = threadIdx.x;
  float* frow = feat + (size_t)blockIdx.x * KF;
  if (tid < 96){
    int c = tid;
    float pv[7];
    #pragma unroll
    for (int l=0;l<7;l++) pv[l] = p[((size_t)b*300 + S + l)*96 + c];
    float run = 0.f;
    #pragma unroll
    for (int l=0;l<6;l++){
      float d = (l < len) ? (pv[l+1]-pv[l]) : 0.f;
      ps[l][c] = run; ds[l][c] = d; run += d;
    }
    frow[c] = pv[0];      // start_pos
    frow[96+c] = run;     // s1 (sum of dseg)
  }
  __syncthreads();
  for (int k = tid; k < NPAIR; k += 256){
    int pr = pairs[k];
    int i = pr >> 7, j = pr & 127;
    float q = 0.f;
    #pragma unroll
    for (int l=0;l<6;l++) q += ps[l][i]*ds[l][j] - ps[l][j]*ds[l][i];
    frow[192+k] = 0.5f*q;
  }
}

// ---------------- fp32 GEMM: xw[row][g] = feat . W_ih[g] + (b_ih+b_hh) ------
__global__ __launch_bounds__(256) void kGemm(const float* feat, const float* wih,
                                             const float* bih, const float* bhh,
                                             float* xw, int row0, int nrows){
  __shared__ __align__(16) float As[16][68];
  __shared__ __align__(16) float Bs[16][68];
  int tid = threadIdx.x;
  int rowBase = blockIdx.x * 64;
  int colBase = blockIdx.y * 64;
  int tx = tid % 16, ty = tid / 16;
  float acc[4][4] = {};
  int lr = tid / 4;            // 0..63
  int lk = (tid % 4) * 4;      // 0,4,8,12
  bool rowOk = (rowBase + lr) < nrows;
  const float* fbase = feat + (size_t)(rowBase+lr)*KF + lk;
  const float* wbase = wih  + (size_t)(colBase+lr)*KF + lk;
  for (int k0 = 0; k0 < KF; k0 += 16){
    float4 a = rowOk ? *(const float4*)(fbase + k0) : make_float4(0.f,0.f,0.f,0.f);
    float4 w = *(const float4*)(wbase + k0);
    As[lk+0][lr]=a.x; As[lk+1][lr]=a.y; As[lk+2][lr]=a.z; As[lk+3][lr]=a.w;
    Bs[lk+0][lr]=w.x; Bs[lk+1][lr]=w.y; Bs[lk+2][lr]=w.z; Bs[lk+3][lr]=w.w;
    __syncthreads();
    #pragma unroll
    for (int kk=0; kk<16; kk++){
      float4 av = *(const float4*)&As[kk][ty*4];
      float4 bv = *(const float4*)&Bs[kk][tx*4];
      float aa[4] = {av.x,av.y,av.z,av.w};
      float bb[4] = {bv.x,bv.y,bv.z,bv.w};
      #pragma unroll
      for (int i2=0;i2<4;i2++)
        #pragma unroll
        for (int j2=0;j2<4;j2++) acc[i2][j2] += aa[i2]*bb[j2];
    }
    __syncthreads();
  }
  #pragma unroll
  for (int i2=0;i2<4;i2++){
    int r = rowBase + ty*4 + i2;
    if (r < nrows){
      #pragma unroll
      for (int j2=0;j2<4;j2++){
        int cg = colBase + tx*4 + j2;
        xw[(size_t)(row0 + r)*G4 + cg] = acc[i2][j2] + bih[cg] + bhh[cg];
      }
    }
  }
}

// ---------------- LSTM: 200 independent recurrences, W_hh in registers -----
__global__ __launch_bounds__(384) void kLstm(const float* xw, const float* whh, float* hsum){
  int b = blockIdx.x;
  int g = threadIdx.x;           // 0..383 (one gate row each)
  __shared__ __align__(16) float h_s[96];
  __shared__ float gbuf[384];
  float wreg[96];
  #pragma unroll
  for (int k=0;k<96;k++) wreg[k] = whh[(size_t)g*96 + k];
  float cval = 0.f, hacc = 0.f;
  if (g < 96) h_s[g] = 0.f;
  __syncthreads();
  const float* xrow = xw + (size_t)b*50*G4;
  for (int t=0;t<50;t++){
    float acc = xrow[t*G4 + g];
    #pragma unroll
    for (int k=0;k<96;k+=4){
      float4 h4 = *(const float4*)&h_s[k];
      acc += wreg[k]*h4.x + wreg[k+1]*h4.y + wreg[k+2]*h4.z + wreg[k+3]*h4.w;
    }
    gbuf[g] = acc;
    __syncthreads();
    if (g < 96){
      float ig = gbuf[g], fg = gbuf[96+g], gg = gbuf[192+g], og = gbuf[288+g];
      float si = 1.f/(1.f+expf(-ig));
      float sf = 1.f/(1.f+expf(-fg));
      float so = 1.f/(1.f+expf(-og));
      cval = sf*cval + si*tanhf(gg);
      float h = so * tanhf(cval);
      h_s[g] = h;
      hacc += h;
    }
    __syncthreads();
  }
  if (g < 96) hsum[(size_t)b*96 + g] = hacc;
}

// ---------------- head: pool over (m, v, s) then FC -------------------------
__global__ void kOut(const float* hsum, const float* wfc, const float* bfc, float* out){
  int n = blockIdx.x;
  __shared__ float pool[96];
  int tid = threadIdx.x;   // 128
  if (tid < 96){
    float a = 0.f;
    for (int mv=0; mv<50; mv++) a += hsum[((size_t)(n*50 + mv))*96 + tid];
    pool[tid] = a / 2500.f;
  }
  __syncthreads();
  if (tid < 60){
    float a = bfc[tid];
    for (int o=0;o<96;o++) a += pool[o]*wfc[tid*96+o];
    out[n*60+tid] = a;
  }
}

extern "C" void kernel_launch(void* const* d_in, const int* in_sizes, int n_in,
                              void* d_out, int out_size, void* d_ws, size_t ws_size,
                              hipStream_t stream){
  const float* x     = (const float*)d_in[0];
  const float* bn_g  = (const float*)d_in[1];
  const float* bn_b  = (const float*)d_in[2];
  const float* bn_m  = (const float*)d_in[3];
  const float* bn_v  = (const float*)d_in[4];
  const float* Ap    = (const float*)d_in[5];
  const float* Ar    = (const float*)d_in[6];
  const float* Wg    = (const float*)d_in[7];
  const float* bg    = (const float*)d_in[8];
  const float* bn2_g = (const float*)d_in[9];
  const float* bn2_b = (const float*)d_in[10];
  const float* bn2_m = (const float*)d_in[11];
  const float* bn2_v = (const float*)d_in[12];
  const float* wih   = (const float*)d_in[13];
  const float* whh   = (const float*)d_in[14];
  const float* bih   = (const float*)d_in[15];
  const float* bhh   = (const float*)d_in[16];
  const float* wfc   = (const float*)d_in[17];
  const float* bfc   = (const float*)d_in[18];
  float* out = (float*)d_out;

  float* ws   = (float*)d_ws;
  float* geff = ws;                       // 360000
  float* beff = geff + 360000;            // 4800
  int*   pairs= (int*)(beff + 4800);      // 4560
  float* pbuf = beff + 4800 + 4560;       // 5,760,000  (200*300*96)
  float* xw   = pbuf + 5760000;           // 3,840,000  (200*50*384)
  float* hsum = xw + 3840000;             // 19,200
  float* feat = hsum + 19200;             // chunk * 4752

  size_t fixedf = 360000u + 4800u + 4560u + 5760000u + 3840000u + 19200u;
  long long availf = (long long)(ws_size/4) - (long long)fixedf;
  int chunk = 64;
  if (availf > 0){
    long long c = availf / KF;
    if (c > 10000) c = 10000;
    chunk = (int)c;
  }
  chunk &= ~63;                 // multiple of 64 for GEMM tiling
  if (chunk < 64) chunk = 64;

  kGeff<<<(2*96*25*75 + 255)/256, 256, 0, stream>>>(bn_g, bn_v, Ap, Ar, Wg, bn2_g, bn2_v, geff);
  kBeff<<<(2*96*25 + 255)/256, 256, 0, stream>>>(bn_g, bn_b, bn_m, bn_v, Ap, Ar, Wg, bg,
                                                 bn2_g, bn2_b, bn2_m, bn2_v, beff);
  kPairs<<<(NPAIR + 255)/256, 256, 0, stream>>>(pairs);
  kP<<<dim3(30, 8), 256, 0, stream>>>(x, geff, beff, pbuf);

  for (int r0 = 0; r0 < 10000; r0 += chunk){
    int nr = 10000 - r0; if (nr > chunk) nr = chunk;
    kFeat<<<nr, 256, 0, stream>>>(pbuf, pairs, feat, r0);
    kGemm<<<dim3((nr + 63)/64, G4/64), 256, 0, stream>>>(feat, wih, bih, bhh, xw, r0, nr);
  }

  kLstm<<<200, 384, 0, stream>>>(xw, whh, hsum);
  kOut<<<4, 128, 0, stream>>>(hsum, wfc, bfc, out);
}

// Round 5
// 1294.096 us; speedup vs baseline: 1.0002x; 1.0002x over previous
//
#include <hip/hip_runtime.h>
#include <math.h>

#define KF 4752          // feature dim: 96 + 96 + 4560
#define G4 384           // 4*C1 gates
#define NPAIR 4560
#define EPSBN 1e-5f

// Segment geometry for T=300, N_SEG=50 (derived exactly, incl. banker's
// rounding of linspace at i=25: 150.5 -> 150).
__device__ __forceinline__ int seg_start(int s){ return (s<=24)? 6*s : 149 + 6*(s-25); }
__device__ __forceinline__ int seg_len(int s){ return (s==24)?5:6; }

// ---------------- precompute: Geff[m][o][v][c*25+u], Beff[m][o][v], pairs ----
__global__ void kGeff(const float* bn_g, const float* bn_v,
                      const float* Ap, const float* Ar, const float* Wg,
                      const float* bn2_g, const float* bn2_v, float* geff){
  int idx = blockIdx.x*256 + threadIdx.x;
  if (idx >= 2*96*25*75) return;
  int cu = idx % 75; int rest = idx/75;
  int v = rest % 25; rest /= 25;
  int o = rest % 96; int m = rest / 96;
  int c = cu/25, u = cu%25;
  int ch = (m*25+u)*3 + c;
  float s1 = bn_g[ch] / sqrtf(bn_v[ch] + EPSBN);
  float s2 = bn2_g[o] / sqrtf(bn2_v[o] + EPSBN);
  float acc = 0.f;
  for (int k=0;k<13;k++){
    float a = Ap[(k*25+v)*25+u] + Ar[(k*25+v)*25+u];
    acc += Wg[o*39 + k*3 + c] * a;
  }
  geff[idx] = acc * s1 * s2;
}

__global__ void kBeff(const float* bn_g,const float* bn_b,const float* bn_m,const float* bn_v,
                      const float* Ap,const float* Ar,const float* Wg,const float* bg,
                      const float* bn2_g,const float* bn2_b,const float* bn2_m,const float* bn2_v,
                      float* beff){
  int idx = blockIdx.x*256+threadIdx.x;
  if (idx >= 2*96*25) return;
  int v = idx%25; int rest = idx/25; int o = rest%96; int m = rest/96;
  float acc = 0.f;
  for (int k=0;k<13;k++) for(int c=0;c<3;c++){
    float w = Wg[o*39+k*3+c];
    for (int u=0;u<25;u++){
      int ch = (m*25+u)*3+c;
      float s1 = bn_g[ch]/sqrtf(bn_v[ch]+EPSBN);
      float t1 = bn_b[ch] - bn_m[ch]*s1;
      acc += w * (Ap[(k*25+v)*25+u]+Ar[(k*25+v)*25+u]) * t1;
    }
  }
  acc += bg[o];
  float s2 = bn2_g[o]/sqrtf(bn2_v[o]+EPSBN);
  beff[idx] = s2*(acc - bn2_m[o]) + bn2_b[o];
}

__global__ void kPairs(int* pairs){
  int k = blockIdx.x*256+threadIdx.x;
  if (k >= NPAIR) return;
  int i=0, rem=k;
  while (rem >= 95 - i){ rem -= (95 - i); i++; }
  int j = i + 1 + rem;
  pairs[k] = (i<<7) | j;
}

// ---------------- p[b=nm*25+v][t][o] = relu(sum_cu Geff*x + Beff) -----------
#define TTILE 10
__global__ __launch_bounds__(256) void kP(const float* x, const float* geff, const float* beff, float* p){
  int nm = blockIdx.y;            // 0..7  (n*2+m)
  int t0 = blockIdx.x * TTILE;
  int m  = nm % 2;
  __shared__ float xs[75*TTILE];
  int tid = threadIdx.x;
  for (int li = tid; li < 75*TTILE; li += 256){
    int u = li % 25; int rest = li/25; int tt = rest % TTILE; int c = rest / TTILE;
    xs[(c*25+u)*TTILE + tt] = x[(((size_t)nm*3 + c)*300 + (t0+tt))*25 + u];
  }
  __syncthreads();
  for (int ow = tid; ow < 2400; ow += 256){
    int o = ow % 96, v = ow / 96;
    const float* g = geff + ((size_t)(m*96+o)*25 + v)*75;
    float b = beff[(m*96+o)*25+v];
    float acc[TTILE];
    #pragma unroll
    for (int t=0;t<TTILE;t++) acc[t] = b;
    for (int cu=0; cu<75; cu++){
      float gv = g[cu];
      #pragma unroll
      for (int t=0;t<TTILE;t++) acc[t] += gv * xs[cu*TTILE+t];
    }
    #pragma unroll
    for (int t=0;t<TTILE;t++)
      p[((size_t)(nm*25+v)*300 + t0+t)*96 + o] = fmaxf(acc[t], 0.f);
  }
}

// ---------------- feat rows: [start(96) | s1(96) | ls2(4560)] ---------------
__global__ __launch_bounds__(256) void kFeat(const float* p, const int* pairs, float* feat, int row0){
  int row = row0 + blockIdx.x;
  int b = row / 50, s = row % 50;
  int S = seg_start(s), len = seg_len(s);
  __shared__ float ps[6][96];
  __shared__ float ds[6][96];
  int tid = threadIdx.x;
  float* frow = feat + (size_t)blockIdx.x * KF;
  if (tid < 96){
    int c = tid;
    float pv[7];
    #pragma unroll
    for (int l=0;l<7;l++) pv[l] = p[((size_t)b*300 + S + l)*96 + c];
    float run = 0.f;
    #pragma unroll
    for (int l=0;l<6;l++){
      float d = (l < len) ? (pv[l+1]-pv[l]) : 0.f;
      ps[l][c] = run; ds[l][c] = d; run += d;
    }
    frow[c] = pv[0];      // start_pos
    frow[96+c] = run;     // s1 (sum of dseg)
  }
  __syncthreads();
  for (int k = tid; k < NPAIR; k += 256){
    int pr = pairs[k];
    int i = pr >> 7, j = pr & 127;
    float q = 0.f;
    #pragma unroll
    for (int l=0;l<6;l++) q += ps[l][i]*ds[l][j] - ps[l][j]*ds[l][i];
    frow[192+k] = 0.5f*q;
  }
}

// ---------------- fp32 GEMM: xw[row][g] = feat . W_ih[g] + (b_ih+b_hh) ------
__global__ __launch_bounds__(256) void kGemm(const float* feat, const float* wih,
                                             const float* bih, const float* bhh,
                                             float* xw, int row0, int nrows){
  __shared__ __align__(16) float As[16][68];
  __shared__ __align__(16) float Bs[16][68];
  int tid = threadIdx.x;
  int rowBase = blockIdx.x * 64;
  int colBase = blockIdx.y * 64;
  int tx = tid % 16, ty = tid / 16;
  float acc[4][4] = {};
  int lr = tid / 4;            // 0..63
  int lk = (tid % 4) * 4;      // 0,4,8,12
  bool rowOk = (rowBase + lr) < nrows;
  const float* fbase = feat + (size_t)(rowBase+lr)*KF + lk;
  const float* wbase = wih  + (size_t)(colBase+lr)*KF + lk;
  for (int k0 = 0; k0 < KF; k0 += 16){
    float4 a = rowOk ? *(const float4*)(fbase + k0) : make_float4(0.f,0.f,0.f,0.f);
    float4 w = *(const float4*)(wbase + k0);
    As[lk+0][lr]=a.x; As[lk+1][lr]=a.y; As[lk+2][lr]=a.z; As[lk+3][lr]=a.w;
    Bs[lk+0][lr]=w.x; Bs[lk+1][lr]=w.y; Bs[lk+2][lr]=w.z; Bs[lk+3][lr]=w.w;
    __syncthreads();
    #pragma unroll
    for (int kk=0; kk<16; kk++){
      float4 av = *(const float4*)&As[kk][ty*4];
      float4 bv = *(const float4*)&Bs[kk][tx*4];
      float aa[4] = {av.x,av.y,av.z,av.w};
      float bb[4] = {bv.x,bv.y,bv.z,bv.w};
      #pragma unroll
      for (int i2=0;i2<4;i2++)
        #pragma unroll
        for (int j2=0;j2<4;j2++) acc[i2][j2] += aa[i2]*bb[j2];
    }
    __syncthreads();
  }
  #pragma unroll
  for (int i2=0;i2<4;i2++){
    int r = rowBase + ty*4 + i2;
    if (r < nrows){
      #pragma unroll
      for (int j2=0;j2<4;j2++){
        int cg = colBase + tx*4 + j2;
        xw[(size_t)(row0 + r)*G4 + cg] = acc[i2][j2] + bih[cg] + bhh[cg];
      }
    }
  }
}

// ---------------- LSTM: 200 independent recurrences, W_hh in registers -----
__global__ __launch_bounds__(384) void kLstm(const float* xw, const float* whh, float* hsum){
  int b = blockIdx.x;
  int g = threadIdx.x;           // 0..383 (one gate row each)
  __shared__ __align__(16) float h_s[96];
  __shared__ float gbuf[384];
  float wreg[96];
  #pragma unroll
  for (int k=0;k<96;k++) wreg[k] = whh[(size_t)g*96 + k];
  float cval = 0.f, hacc = 0.f;
  if (g < 96) h_s[g] = 0.f;
  __syncthreads();
  const float* xrow = xw + (size_t)b*50*G4;
  for (int t=0;t<50;t++){
    float acc = xrow[t*G4 + g];
    #pragma unroll
    for (int k=0;k<96;k+=4){
      float4 h4 = *(const float4*)&h_s[k];
      acc += wreg[k]*h4.x + wreg[k+1]*h4.y + wreg[k+2]*h4.z + wreg[k+3]*h4.w;
    }
    gbuf[g] = acc;
    __syncthreads();
    if (g < 96){
      float ig = gbuf[g], fg = gbuf[96+g], gg = gbuf[192+g], og = gbuf[288+g];
      float si = 1.f/(1.f+expf(-ig));
      float sf = 1.f/(1.f+expf(-fg));
      float so = 1.f/(1.f+expf(-og));
      cval = sf*cval + si*tanhf(gg);
      float h = so * tanhf(cval);
      h_s[g] = h;
      hacc += h;
    }
    __syncthreads();
  }
  if (g < 96) hsum[(size_t)b*96 + g] = hacc;
}

// ---------------- head: pool over (m, v, s) then FC -------------------------
__global__ void kOut(const float* hsum, const float* wfc, const float* bfc, float* out){
  int n = blockIdx.x;
  __shared__ float pool[96];
  int tid = threadIdx.x;   // 128
  if (tid < 96){
    float a = 0.f;
    for (int mv=0; mv<50; mv++) a += hsum[((size_t)(n*50 + mv))*96 + tid];
    pool[tid] = a / 2500.f;
  }
  __syncthreads();
  if (tid < 60){
    float a = bfc[tid];
    for (int o=0;o<96;o++) a += pool[o]*wfc[tid*96+o];
    out[n*60+tid] = a;
  }
}

extern "C" void kernel_launch(void* const* d_in, const int* in_sizes, int n_in,
                              void* d_out, int out_size, void* d_ws, size_t ws_size,
                              hipStream_t stream){
  const float* x     = (const float*)d_in[0];
  const float* bn_g  = (const float*)d_in[1];
  const float* bn_b  = (const float*)d_in[2];
  const float* bn_m  = (const float*)d_in[3];
  const float* bn_v  = (const float*)d_in[4];
  const float* Ap    = (const float*)d_in[5];
  const float* Ar    = (const float*)d_in[6];
  const float* Wg    = (const float*)d_in[7];
  const float* bg    = (const float*)d_in[8];
  const float* bn2_g = (const float*)d_in[9];
  const float* bn2_b = (const float*)d_in[10];
  const float* bn2_m = (const float*)d_in[11];
  const float* bn2_v = (const float*)d_in[12];
  const float* wih   = (const float*)d_in[13];
  const float* whh   = (const float*)d_in[14];
  const float* bih   = (const float*)d_in[15];
  const float* bhh   = (const float*)d_in[16];
  const float* wfc   = (const float*)d_in[17];
  const float* bfc   = (const float*)d_in[18];
  float* out = (float*)d_out;

  float* ws   = (float*)d_ws;
  float* geff = ws;                       // 360000
  float* beff = geff + 360000;            // 4800
  int*   pairs= (int*)(beff + 4800);      // 4560
  float* pbuf = beff + 4800 + 4560;       // 5,760,000  (200*300*96)
  float* xw   = pbuf + 5760000;           // 3,840,000  (200*50*384)
  float* hsum = xw + 3840000;             // 19,200
  float* feat = hsum + 19200;             // chunk * 4752

  size_t fixedf = 360000u + 4800u + 4560u + 5760000u + 3840000u + 19200u;
  long long availf = (long long)(ws_size/4) - (long long)fixedf;
  int chunk = 64;
  if (availf > 0){
    long long c = availf / KF;
    if (c > 10000) c = 10000;
    chunk = (int)c;
  }
  chunk &= ~63;                 // multiple of 64 for GEMM tiling
  if (chunk < 64) chunk = 64;

  kGeff<<<(2*96*25*75 + 255)/256, 256, 0, stream>>>(bn_g, bn_v, Ap, Ar, Wg, bn2_g, bn2_v, geff);
  kBeff<<<(2*96*25 + 255)/256, 256, 0, stream>>>(bn_g, bn_b, bn_m, bn_v, Ap, Ar, Wg, bg,
                                                 bn2_g, bn2_b, bn2_m, bn2_v, beff);
  kPairs<<<(NPAIR + 255)/256, 256, 0, stream>>>(pairs);
  kP<<<dim3(30, 8), 256, 0, stream>>>(x, geff, beff, pbuf);

  for (int r0 = 0; r0 < 10000; r0 += chunk){
    int nr = 10000 - r0; if (nr > chunk) nr = chunk;
    kFeat<<<nr, 256, 0, stream>>>(pbuf, pairs, feat, r0);
    kGemm<<<dim3((nr + 63)/64, G4/64), 256, 0, stream>>>(feat, wih, bih, bhh, xw, r0, nr);
  }

  kLstm<<<200, 384, 0, stream>>>(xw, whh, hsum);
  kOut<<<4, 128, 0, stream>>>(hsum, wfc, bfc, out);
}

// Round 6
// 553.301 us; speedup vs baseline: 2.3393x; 2.3389x over previous
//
#include <hip/hip_runtime.h>
#include <math.h>

#define KF 4752          // real feature dim: 96 + 96 + 4560
#define KP 4768          // padded to 32*149
#define KSTEPS 149
#define G4 384           // 4*C1 gates
#define NPAIR 4560
#define EPSBN 1e-5f
#define XWHALF 3840000   // 10000*384 floats per K-half partial

typedef float f32x4 __attribute__((ext_vector_type(4)));
typedef short s16x8 __attribute__((ext_vector_type(8)));

__device__ __forceinline__ unsigned short f2bf(float x){
  unsigned u = __float_as_uint(x);
  return (unsigned short)((u + 0x7fffu + ((u>>16)&1u)) >> 16);
}
__device__ __forceinline__ float bf2f(unsigned short h){
  return __uint_as_float(((unsigned)h)<<16);
}

__device__ __forceinline__ int seg_start(int s){ return (s<=24)? 6*s : 149 + 6*(s-25); }
__device__ __forceinline__ int seg_len(int s){ return (s==24)?5:6; }

// ---------------- precompute: geffT[m][cu][v*96+o], beffT[m][v*96+o] --------
__global__ void kGeff(const float* bn_g, const float* bn_v,
                      const float* Ap, const float* Ar, const float* Wg,
                      const float* bn2_g, const float* bn2_v, float* geffT){
  int idx = blockIdx.x*256 + threadIdx.x;
  if (idx >= 2*96*25*75) return;
  int cu = idx % 75; int rest = idx/75;
  int v = rest % 25; rest /= 25;
  int o = rest % 96; int m = rest / 96;
  int c = cu/25, u = cu%25;
  int ch = (m*25+u)*3 + c;
  float s1 = bn_g[ch] / sqrtf(bn_v[ch] + EPSBN);
  float s2 = bn2_g[o] / sqrtf(bn2_v[o] + EPSBN);
  float acc = 0.f;
  for (int k=0;k<13;k++){
    float a = Ap[(k*25+v)*25+u] + Ar[(k*25+v)*25+u];
    acc += Wg[o*39 + k*3 + c] * a;
  }
  geffT[((size_t)(m*75+cu))*2400 + v*96 + o] = acc * s1 * s2;
}

__global__ void kBeff(const float* bn_g,const float* bn_b,const float* bn_m,const float* bn_v,
                      const float* Ap,const float* Ar,const float* Wg,const float* bg,
                      const float* bn2_g,const float* bn2_b,const float* bn2_m,const float* bn2_v,
                      float* beffT){
  int idx = blockIdx.x*256+threadIdx.x;
  if (idx >= 2*96*25) return;
  int v = idx%25; int rest = idx/25; int o = rest%96; int m = rest/96;
  float acc = 0.f;
  for (int k=0;k<13;k++) for(int c=0;c<3;c++){
    float w = Wg[o*39+k*3+c];
    for (int u=0;u<25;u++){
      int ch = (m*25+u)*3+c;
      float s1 = bn_g[ch]/sqrtf(bn_v[ch]+EPSBN);
      float t1 = bn_b[ch] - bn_m[ch]*s1;
      acc += w * (Ap[(k*25+v)*25+u]+Ar[(k*25+v)*25+u]) * t1;
    }
  }
  acc += bg[o];
  float s2 = bn2_g[o]/sqrtf(bn2_v[o]+EPSBN);
  beffT[m*2400 + v*96 + o] = s2*(acc - bn2_m[o]) + bn2_b[o];
}

__global__ void kPairs(int* pairs){
  int k = blockIdx.x*256+threadIdx.x;
  if (k >= NPAIR) return;
  int i=0, rem=k;
  while (rem >= 95 - i){ rem -= (95 - i); i++; }
  int j = i + 1 + rem;
  pairs[k] = (i<<7) | j;
}

// ---------------- W_ih split into bf16 hi/lo, K-padded ----------------------
__global__ void kWsplit(const float* w, unsigned short* whi, unsigned short* wlo){
  int idx = blockIdx.x*256 + threadIdx.x;
  if (idx >= G4*KP) return;
  int g = idx / KP, k = idx % KP;
  float v = (k < KF) ? w[(size_t)g*KF + k] : 0.f;
  unsigned short h = f2bf(v);
  whi[idx] = h;
  wlo[idx] = f2bf(v - bf2f(h));
}

// ---------------- p[b=nm*25+v][t][o] = relu(sum_cu geff*x + beff) -----------
#define TTILE 10
__global__ __launch_bounds__(256) void kP(const float* x, const float* geffT, const float* beffT, float* p){
  int nm = blockIdx.y;            // 0..7
  int t0 = blockIdx.x * TTILE;
  int m  = nm % 2;
  __shared__ float xs[75*TTILE];
  int tid = threadIdx.x;
  for (int li = tid; li < 75*TTILE; li += 256){
    int u = li % 25; int rest = li/25; int tt = rest % TTILE; int c = rest / TTILE;
    xs[(c*25+u)*TTILE + tt] = x[(((size_t)nm*3 + c)*300 + (t0+tt))*25 + u];
  }
  __syncthreads();
  const float* gT = geffT + (size_t)m*75*2400;
  for (int ow = tid; ow < 2400; ow += 256){
    int o = ow % 96, v = ow / 96;
    float b = beffT[m*2400 + ow];
    float acc[TTILE];
    #pragma unroll
    for (int t=0;t<TTILE;t++) acc[t] = b;
    for (int cu=0; cu<75; cu++){
      float gv = gT[(size_t)cu*2400 + ow];   // coalesced across lanes
      #pragma unroll
      for (int t=0;t<TTILE;t++) acc[t] += gv * xs[cu*TTILE+t];
    }
    #pragma unroll
    for (int t=0;t<TTILE;t++)
      p[((size_t)(nm*25+v)*300 + t0+t)*96 + o] = fmaxf(acc[t], 0.f);
  }
}

// ---------------- feat rows -> split bf16 hi/lo ------------------------------
__global__ __launch_bounds__(256) void kFeat(const float* p, const int* pairs,
                                             unsigned short* fhi, unsigned short* flo, int row0){
  int row = row0 + blockIdx.x;
  int b = row / 50, s = row % 50;
  int S = seg_start(s), len = seg_len(s);
  __shared__ float ps[6][96];
  __shared__ float ds[6][96];
  int tid = threadIdx.x;
  size_t base = (size_t)blockIdx.x * KP;
  if (tid < 96){
    int c = tid;
    float pv[7];
    #pragma unroll
    for (int l=0;l<7;l++) pv[l] = p[((size_t)b*300 + S + l)*96 + c];
    float run = 0.f;
    #pragma unroll
    for (int l=0;l<6;l++){
      float d = (l < len) ? (pv[l+1]-pv[l]) : 0.f;
      ps[l][c] = run; ds[l][c] = d; run += d;
    }
    unsigned short h0 = f2bf(pv[0]);
    fhi[base + c] = h0; flo[base + c] = f2bf(pv[0] - bf2f(h0));
    unsigned short h1 = f2bf(run);
    fhi[base + 96 + c] = h1; flo[base + 96 + c] = f2bf(run - bf2f(h1));
  } else if (tid < 112){
    int c = KF + (tid - 96);          // zero the K-pad
    fhi[base + c] = 0; flo[base + c] = 0;
  }
  __syncthreads();
  for (int k = tid; k < NPAIR; k += 256){
    int pr = pairs[k];
    int i = pr >> 7, j = pr & 127;
    float q = 0.f;
    #pragma unroll
    for (int l=0;l<6;l++) q += ps[l][i]*ds[l][j] - ps[l][j]*ds[l][i];
    q *= 0.5f;
    unsigned short h = f2bf(q);
    fhi[base + 192 + k] = h; flo[base + 192 + k] = f2bf(q - bf2f(h));
  }
}

// ---------------- MFMA split-bf16 GEMM: xw_partial = feat . W_ih^T ----------
// Tile 128x192, BK=32, grid (col=2, z=2, rowblk). 3-product split accumulate.
__device__ __forceinline__ void gload16(const void* g, void* l){
  __builtin_amdgcn_global_load_lds(
      (const __attribute__((address_space(1))) void*)g,
      (__attribute__((address_space(3))) void*)l, 16, 0, 0);
}

__global__ __launch_bounds__(256) void kGemm(
    const unsigned short* __restrict__ fhi, const unsigned short* __restrict__ flo,
    const unsigned short* __restrict__ whi, const unsigned short* __restrict__ wlo,
    float* __restrict__ xw, int chunkRow0, int nrows)
{
  // LDS buffer layout (shorts): Ah[0,4096) Al[4096,8192) Bh[8192,14336) Bl[14336,20480)
  __shared__ unsigned short lds[2][20480];   // 80 KiB
  int tid  = threadIdx.x;
  int lane = tid & 63, w = tid >> 6;
  int colBase = blockIdx.x * 192;
  int zz      = blockIdx.y;
  int mblk    = blockIdx.z;
  int zbase   = zz * 75;
  int zSteps  = zz ? (KSTEPS - 75) : 75;

  // staging: 2560 16B-chunks, 10 per thread; LDS dest linear, global src
  // granule-swizzled (involution g ^= (row>>1)&3) so ds_read_b128 is ~2-way.
  const unsigned short* gptr[10];
  int ldsOff[10];
  #pragma unroll
  for (int q=0;q<10;q++){
    int c = (w*10 + q)*64 + lane;
    const unsigned short* bp; int rr;
    if (c < 512)        { rr = c;        bp = fhi + (size_t)(mblk*128 + (rr>>2))*KP; }
    else if (c < 1024)  { rr = c-512;    bp = flo + (size_t)(mblk*128 + (rr>>2))*KP; }
    else if (c < 1792)  { rr = c-1024;   bp = whi + (size_t)(colBase  + (rr>>2))*KP; }
    else                { rr = c-1792;   bp = wlo + (size_t)(colBase  + (rr>>2))*KP; }
    int row = rr>>2, gl = rr&3;
    int gs = gl ^ ((row>>1)&3);
    gptr[q]  = bp + gs*8;
    ldsOff[q] = (w*10 + q)*512;
  }

  // frag ds_read offsets (shorts)
  int wm = w & 1, wn = w >> 1;
  int gsel = lane >> 4;
  int aoff[4], boff[6];
  #pragma unroll
  for (int fm=0; fm<4; fm++){
    int r = wm*64 + fm*16 + (lane&15);
    aoff[fm] = r*32 + ((gsel ^ ((r>>1)&3))*8);
  }
  #pragma unroll
  for (int fn=0; fn<6; fn++){
    int r = wn*96 + fn*16 + (lane&15);
    boff[fn] = 8192 + r*32 + ((gsel ^ ((r>>1)&3))*8);
  }

  f32x4 acc[4][6];
  #pragma unroll
  for (int fm=0;fm<4;fm++)
    #pragma unroll
    for (int fn=0;fn<6;fn++) acc[fm][fn] = (f32x4){0.f,0.f,0.f,0.f};

  // prologue stage
  #pragma unroll
  for (int q=0;q<10;q++) gload16(gptr[q] + (size_t)zbase*32, &lds[0][ldsOff[q]]);

  int cur = 0;
  for (int t=0; t<zSteps; ++t){
    __syncthreads();                       // drains vmcnt: buf[cur] ready
    if (t+1 < zSteps){
      size_t ko = (size_t)(zbase + t + 1)*32;
      #pragma unroll
      for (int q=0;q<10;q++) gload16(gptr[q] + ko, &lds[cur^1][ldsOff[q]]);
    }
    const unsigned short* L = lds[cur];
    s16x8 ah[4], al[4], bh[6], bl[6];
    #pragma unroll
    for (int fm=0;fm<4;fm++){
      ah[fm] = *(const s16x8*)(L + aoff[fm]);
      al[fm] = *(const s16x8*)(L + aoff[fm] + 4096);
    }
    #pragma unroll
    for (int fn=0;fn<6;fn++){
      bh[fn] = *(const s16x8*)(L + boff[fn]);
      bl[fn] = *(const s16x8*)(L + boff[fn] + 6144);
    }
    #pragma unroll
    for (int fm=0;fm<4;fm++)
      #pragma unroll
      for (int fn=0;fn<6;fn++){
        acc[fm][fn] = __builtin_amdgcn_mfma_f32_16x16x32_bf16(ah[fm], bh[fn], acc[fm][fn], 0,0,0);
        acc[fm][fn] = __builtin_amdgcn_mfma_f32_16x16x32_bf16(ah[fm], bl[fn], acc[fm][fn], 0,0,0);
        acc[fm][fn] = __builtin_amdgcn_mfma_f32_16x16x32_bf16(al[fm], bh[fn], acc[fm][fn], 0,0,0);
      }
    cur ^= 1;
  }

  // epilogue: C/D layout col=lane&15, row=(lane>>4)*4+reg (m89/m91)
  int rl = (lane>>4)*4, cl = lane&15;
  float* outp = xw + (size_t)zz*XWHALF;
  #pragma unroll
  for (int fm=0;fm<4;fm++){
    #pragma unroll
    for (int fn=0;fn<6;fn++){
      int gr0 = mblk*128 + wm*64 + fm*16 + rl;
      int gc  = colBase + wn*96 + fn*16 + cl;
      f32x4 v = acc[fm][fn];
      #pragma unroll
      for (int r=0;r<4;r++){
        int gr = gr0 + r;
        if (gr < nrows)
          outp[(size_t)(chunkRow0 + gr)*G4 + gc] = v[r];
      }
    }
  }
}

// ---------------- LSTM: sums both K-half partials + bias --------------------
__global__ __launch_bounds__(384) void kLstm(const float* xw, const float* whh,
                                             const float* bih, const float* bhh, float* hsum){
  int b = blockIdx.x;
  int g = threadIdx.x;           // 0..383
  __shared__ __align__(16) float h_s[96];
  __shared__ float gbuf[384];
  float wreg[96];
  #pragma unroll
  for (int k=0;k<96;k++) wreg[k] = whh[(size_t)g*96 + k];
  float breg = bih[g] + bhh[g];
  float cval = 0.f, hacc = 0.f;
  if (g < 96) h_s[g] = 0.f;
  __syncthreads();
  const float* xrow  = xw + (size_t)b*50*G4;
  const float* xrow2 = xrow + XWHALF;
  for (int t=0;t<50;t++){
    float acc = xrow[t*G4 + g] + xrow2[t*G4 + g] + breg;
    #pragma unroll
    for (int k=0;k<96;k+=4){
      float4 h4 = *(const float4*)&h_s[k];
      acc += wreg[k]*h4.x + wreg[k+1]*h4.y + wreg[k+2]*h4.z + wreg[k+3]*h4.w;
    }
    gbuf[g] = acc;
    __syncthreads();
    if (g < 96){
      float ig = gbuf[g], fg = gbuf[96+g], gg = gbuf[192+g], og = gbuf[288+g];
      float si = 1.f/(1.f+expf(-ig));
      float sf = 1.f/(1.f+expf(-fg));
      float so = 1.f/(1.f+expf(-og));
      cval = sf*cval + si*tanhf(gg);
      float h = so * tanhf(cval);
      h_s[g] = h;
      hacc += h;
    }
    __syncthreads();
  }
  if (g < 96) hsum[(size_t)b*96 + g] = hacc;
}

// ---------------- head ------------------------------------------------------
__global__ void kOut(const float* hsum, const float* wfc, const float* bfc, float* out){
  int n = blockIdx.x;
  __shared__ float pool[96];
  int tid = threadIdx.x;   // 128
  if (tid < 96){
    float a = 0.f;
    for (int mv=0; mv<50; mv++) a += hsum[((size_t)(n*50 + mv))*96 + tid];
    pool[tid] = a / 2500.f;
  }
  __syncthreads();
  if (tid < 60){
    float a = bfc[tid];
    for (int o=0;o<96;o++) a += pool[o]*wfc[tid*96+o];
    out[n*60+tid] = a;
  }
}

extern "C" void kernel_launch(void* const* d_in, const int* in_sizes, int n_in,
                              void* d_out, int out_size, void* d_ws, size_t ws_size,
                              hipStream_t stream){
  const float* x     = (const float*)d_in[0];
  const float* bn_g  = (const float*)d_in[1];
  const float* bn_b  = (const float*)d_in[2];
  const float* bn_m  = (const float*)d_in[3];
  const float* bn_v  = (const float*)d_in[4];
  const float* Ap    = (const float*)d_in[5];
  const float* Ar    = (const float*)d_in[6];
  const float* Wg    = (const float*)d_in[7];
  const float* bg    = (const float*)d_in[8];
  const float* bn2_g = (const float*)d_in[9];
  const float* bn2_b = (const float*)d_in[10];
  const float* bn2_m = (const float*)d_in[11];
  const float* bn2_v = (const float*)d_in[12];
  const float* wih   = (const float*)d_in[13];
  const float* whh   = (const float*)d_in[14];
  const float* bih   = (const float*)d_in[15];
  const float* bhh   = (const float*)d_in[16];
  const float* wfc   = (const float*)d_in[17];
  const float* bfc   = (const float*)d_in[18];
  float* out = (float*)d_out;

  float* ws    = (float*)d_ws;
  float* geffT = ws;                        // 360,000
  float* beffT = geffT + 360000;            // 4,800
  int*   pairs = (int*)(beffT + 4800);      // 4,560
  float* pbuf  = beffT + 4800 + 4560;       // 5,760,000
  float* xw    = pbuf + 5760000;            // 7,680,000 (two K-half partials)
  float* hsum  = xw + 2*XWHALF;             // 19,200
  unsigned short* whiP = (unsigned short*)(hsum + 19200);   // 384*4768 shorts
  unsigned short* wloP = whiP + (size_t)G4*KP;
  unsigned short* fhi  = wloP + (size_t)G4*KP;              // chunkRows*KP shorts
  // fixed floats so far:
  size_t fixedFloats = 360000u + 4800u + 4560u + 5760000u + 2u*XWHALF + 19200u
                     + (size_t)G4*KP;       // W hi+lo = 2*(G4*KP) shorts = G4*KP floats
  long long availB = (long long)ws_size - (long long)(fixedFloats*4);
  long long perBlk128 = 128LL*KP*2*2;       // hi+lo bf16 per 128 rows
  int blocks128 = (availB > 0) ? (int)(availB / perBlk128) : 1;
  if (blocks128 < 1)  blocks128 = 1;
  if (blocks128 > 79) blocks128 = 79;
  int chunkRows = blocks128 * 128;
  unsigned short* flo = fhi + (size_t)chunkRows*KP;

  kGeff<<<(2*96*25*75 + 255)/256, 256, 0, stream>>>(bn_g, bn_v, Ap, Ar, Wg, bn2_g, bn2_v, geffT);
  kBeff<<<(2*96*25 + 255)/256, 256, 0, stream>>>(bn_g, bn_b, bn_m, bn_v, Ap, Ar, Wg, bg,
                                                 bn2_g, bn2_b, bn2_m, bn2_v, beffT);
  kPairs<<<(NPAIR + 255)/256, 256, 0, stream>>>(pairs);
  kWsplit<<<((G4*KP) + 255)/256, 256, 0, stream>>>(wih, whiP, wloP);
  kP<<<dim3(30, 8), 256, 0, stream>>>(x, geffT, beffT, pbuf);

  for (int r0 = 0; r0 < 10000; r0 += chunkRows){
    int nr = 10000 - r0; if (nr > chunkRows) nr = chunkRows;
    kFeat<<<nr, 256, 0, stream>>>(pbuf, pairs, fhi, flo, r0);
    kGemm<<<dim3(2, 2, (nr + 127)/128), 256, 0, stream>>>(fhi, flo, whiP, wloP, xw, r0, nr);
  }

  kLstm<<<200, 384, 0, stream>>>(xw, whh, bih, bhh, hsum);
  kOut<<<4, 128, 0, stream>>>(hsum, wfc, bfc, out);
}

// Round 7
// 397.708 us; speedup vs baseline: 3.2545x; 1.3912x over previous
//
#include <hip/hip_runtime.h>
#include <math.h>

#define KF 4752          // real feature dim: 96 + 96 + 4560
#define KP 4768          // padded to 32*149
#define KSTEPS 149
#define G4 384           // 4*C1 gates
#define NPAIR 4560
#define EPSBN 1e-5f
#define XWHALF 3840000   // 10000*384 floats per K-half partial

typedef float f32x4 __attribute__((ext_vector_type(4)));
typedef short s16x8 __attribute__((ext_vector_type(8)));

__device__ __forceinline__ unsigned short f2bf(float x){
  unsigned u = __float_as_uint(x);
  return (unsigned short)((u + 0x7fffu + ((u>>16)&1u)) >> 16);
}
__device__ __forceinline__ float bf2f(unsigned short h){
  return __uint_as_float(((unsigned)h)<<16);
}

__device__ __forceinline__ int seg_start(int s){ return (s<=24)? 6*s : 149 + 6*(s-25); }
__device__ __forceinline__ int seg_len(int s){ return (s==24)?5:6; }

// ---------------- precompute: geffT[m][cu][v*96+o], beffT[m][v*96+o] --------
__global__ void kGeff(const float* bn_g, const float* bn_v,
                      const float* Ap, const float* Ar, const float* Wg,
                      const float* bn2_g, const float* bn2_v, float* geffT){
  int idx = blockIdx.x*256 + threadIdx.x;
  if (idx >= 2*96*25*75) return;
  int cu = idx % 75; int rest = idx/75;
  int v = rest % 25; rest /= 25;
  int o = rest % 96; int m = rest / 96;
  int c = cu/25, u = cu%25;
  int ch = (m*25+u)*3 + c;
  float s1 = bn_g[ch] / sqrtf(bn_v[ch] + EPSBN);
  float s2 = bn2_g[o] / sqrtf(bn2_v[o] + EPSBN);
  float acc = 0.f;
  for (int k=0;k<13;k++){
    float a = Ap[(k*25+v)*25+u] + Ar[(k*25+v)*25+u];
    acc += Wg[o*39 + k*3 + c] * a;
  }
  geffT[((size_t)(m*75+cu))*2400 + v*96 + o] = acc * s1 * s2;
}

// one WAVE per output (m,o,v): lanes split the 975 (k,c,u) terms, then
// shfl-reduce. All operands are L2-resident; loads pipeline across lanes.
__global__ __launch_bounds__(256) void kBeff(const float* bn_g,const float* bn_b,const float* bn_m,const float* bn_v,
                      const float* Ap,const float* Ar,const float* Wg,const float* bg,
                      const float* bn2_g,const float* bn2_b,const float* bn2_m,const float* bn2_v,
                      float* beffT){
  int wid  = (blockIdx.x*256 + threadIdx.x) >> 6;   // 0..4799
  int lane = threadIdx.x & 63;
  if (wid >= 2*96*25) return;
  int v = wid % 25; int rest = wid/25; int o = rest % 96; int m = rest/96;
  float acc = 0.f;
  #pragma unroll
  for (int it=0; it<16; ++it){
    int item = it*64 + lane;               // 975 items total
    if (item < 975){
      int k = item / 75; int cu = item % 75; int c = cu/25, u = cu%25;
      int ch = (m*25+u)*3 + c;
      float s1 = bn_g[ch] / sqrtf(bn_v[ch] + EPSBN);
      float t1 = bn_b[ch] - bn_m[ch]*s1;
      float a  = Ap[(k*25+v)*25+u] + Ar[(k*25+v)*25+u];
      acc += Wg[o*39 + k*3 + c] * a * t1;
    }
  }
  #pragma unroll
  for (int off=32; off; off>>=1) acc += __shfl_down(acc, off);
  if (lane == 0){
    acc += bg[o];
    float s2 = bn2_g[o]/sqrtf(bn2_v[o]+EPSBN);
    beffT[m*2400 + v*96 + o] = s2*(acc - bn2_m[o]) + bn2_b[o];
  }
}

__global__ void kPairs(int* pairs){
  int k = blockIdx.x*256+threadIdx.x;
  if (k >= NPAIR) return;
  int i=0, rem=k;
  while (rem >= 95 - i){ rem -= (95 - i); i++; }
  int j = i + 1 + rem;
  pairs[k] = (i<<7) | j;
}

// ---------------- W_ih split into bf16 hi/lo, K-padded ----------------------
__global__ void kWsplit(const float* w, unsigned short* whi, unsigned short* wlo){
  int idx = blockIdx.x*256 + threadIdx.x;
  if (idx >= G4*KP) return;
  int g = idx / KP, k = idx % KP;
  float v = (k < KF) ? w[(size_t)g*KF + k] : 0.f;
  unsigned short h = f2bf(v);
  whi[idx] = h;
  wlo[idx] = f2bf(v - bf2f(h));
}

// ---------------- p[b=nm*25+v][t][o] = relu(sum_cu geff*x + beff) -----------
#define TTILE 10
__global__ __launch_bounds__(256) void kP(const float* x, const float* geffT, const float* beffT, float* p){
  int nm = blockIdx.y;            // 0..7
  int t0 = blockIdx.x * TTILE;
  int m  = nm % 2;
  __shared__ float xs[75*TTILE];
  int tid = threadIdx.x;
  for (int li = tid; li < 75*TTILE; li += 256){
    int u = li % 25; int rest = li/25; int tt = rest % TTILE; int c = rest / TTILE;
    xs[(c*25+u)*TTILE + tt] = x[(((size_t)nm*3 + c)*300 + (t0+tt))*25 + u];
  }
  __syncthreads();
  const float* gT = geffT + (size_t)m*75*2400;
  for (int ow = tid; ow < 2400; ow += 256){
    int o = ow % 96, v = ow / 96;
    float b = beffT[m*2400 + ow];
    float acc[TTILE];
    #pragma unroll
    for (int t=0;t<TTILE;t++) acc[t] = b;
    for (int cu=0; cu<75; cu++){
      float gv = gT[(size_t)cu*2400 + ow];   // coalesced across lanes
      #pragma unroll
      for (int t=0;t<TTILE;t++) acc[t] += gv * xs[cu*TTILE+t];
    }
    #pragma unroll
    for (int t=0;t<TTILE;t++)
      p[((size_t)(nm*25+v)*300 + t0+t)*96 + o] = fmaxf(acc[t], 0.f);
  }
}

// ---------------- feat rows -> split bf16 hi/lo ------------------------------
__global__ __launch_bounds__(256) void kFeat(const float* p, const int* pairs,
                                             unsigned short* fhi, unsigned short* flo, int row0){
  int row = row0 + blockIdx.x;
  int b = row / 50, s = row % 50;
  int S = seg_start(s), len = seg_len(s);
  __shared__ float ps[6][96];
  __shared__ float ds[6][96];
  int tid = threadIdx.x;
  size_t base = (size_t)blockIdx.x * KP;
  if (tid < 96){
    int c = tid;
    float pv[7];
    #pragma unroll
    for (int l=0;l<7;l++) pv[l] = p[((size_t)b*300 + S + l)*96 + c];
    float run = 0.f;
    #pragma unroll
    for (int l=0;l<6;l++){
      float d = (l < len) ? (pv[l+1]-pv[l]) : 0.f;
      ps[l][c] = run; ds[l][c] = d; run += d;
    }
    unsigned short h0 = f2bf(pv[0]);
    fhi[base + c] = h0; flo[base + c] = f2bf(pv[0] - bf2f(h0));
    unsigned short h1 = f2bf(run);
    fhi[base + 96 + c] = h1; flo[base + 96 + c] = f2bf(run - bf2f(h1));
  } else if (tid < 112){
    int c = KF + (tid - 96);          // zero the K-pad
    fhi[base + c] = 0; flo[base + c] = 0;
  }
  __syncthreads();
  for (int k = tid; k < NPAIR; k += 256){
    int pr = pairs[k];
    int i = pr >> 7, j = pr & 127;
    float q = 0.f;
    #pragma unroll
    for (int l=0;l<6;l++) q += ps[l][i]*ds[l][j] - ps[l][j]*ds[l][i];
    q *= 0.5f;
    unsigned short h = f2bf(q);
    fhi[base + 192 + k] = h; flo[base + 192 + k] = f2bf(q - bf2f(h));
  }
}

// ---------------- MFMA split-bf16 GEMM: xw_partial = feat . W_ih^T ----------
// Tile 128x192, BK=32, grid (col=2, z=2, rowblk). 3-product split accumulate.
__device__ __forceinline__ void gload16(const void* g, void* l){
  __builtin_amdgcn_global_load_lds(
      (const __attribute__((address_space(1))) void*)g,
      (__attribute__((address_space(3))) void*)l, 16, 0, 0);
}

__global__ __launch_bounds__(256) void kGemm(
    const unsigned short* __restrict__ fhi, const unsigned short* __restrict__ flo,
    const unsigned short* __restrict__ whi, const unsigned short* __restrict__ wlo,
    float* __restrict__ xw, int chunkRow0, int nrows)
{
  // LDS buffer layout (shorts): Ah[0,4096) Al[4096,8192) Bh[8192,14336) Bl[14336,20480)
  __shared__ unsigned short lds[2][20480];   // 80 KiB
  int tid  = threadIdx.x;
  int lane = tid & 63, w = tid >> 6;
  int colBase = blockIdx.x * 192;
  int zz      = blockIdx.y;
  int mblk    = blockIdx.z;
  int zbase   = zz * 75;
  int zSteps  = zz ? (KSTEPS - 75) : 75;

  // staging: 2560 16B-chunks, 10 per thread; LDS dest linear, global src
  // granule-swizzled (involution g ^= (row>>1)&3) so ds_read_b128 is ~2-way.
  const unsigned short* gptr[10];
  int ldsOff[10];
  #pragma unroll
  for (int q=0;q<10;q++){
    int c = (w*10 + q)*64 + lane;
    const unsigned short* bp; int rr;
    if (c < 512)        { rr = c;        bp = fhi + (size_t)(mblk*128 + (rr>>2))*KP; }
    else if (c < 1024)  { rr = c-512;    bp = flo + (size_t)(mblk*128 + (rr>>2))*KP; }
    else if (c < 1792)  { rr = c-1024;   bp = whi + (size_t)(colBase  + (rr>>2))*KP; }
    else                { rr = c-1792;   bp = wlo + (size_t)(colBase  + (rr>>2))*KP; }
    int row = rr>>2, gl = rr&3;
    int gs = gl ^ ((row>>1)&3);
    gptr[q]  = bp + gs*8;
    ldsOff[q] = (w*10 + q)*512;
  }

  // frag ds_read offsets (shorts)
  int wm = w & 1, wn = w >> 1;
  int gsel = lane >> 4;
  int aoff[4], boff[6];
  #pragma unroll
  for (int fm=0; fm<4; fm++){
    int r = wm*64 + fm*16 + (lane&15);
    aoff[fm] = r*32 + ((gsel ^ ((r>>1)&3))*8);
  }
  #pragma unroll
  for (int fn=0; fn<6; fn++){
    int r = wn*96 + fn*16 + (lane&15);
    boff[fn] = 8192 + r*32 + ((gsel ^ ((r>>1)&3))*8);
  }

  f32x4 acc[4][6];
  #pragma unroll
  for (int fm=0;fm<4;fm++)
    #pragma unroll
    for (int fn=0;fn<6;fn++) acc[fm][fn] = (f32x4){0.f,0.f,0.f,0.f};

  // prologue stage
  #pragma unroll
  for (int q=0;q<10;q++) gload16(gptr[q] + (size_t)zbase*32, &lds[0][ldsOff[q]]);

  int cur = 0;
  for (int t=0; t<zSteps; ++t){
    __syncthreads();                       // drains vmcnt: buf[cur] ready
    if (t+1 < zSteps){
      size_t ko = (size_t)(zbase + t + 1)*32;
      #pragma unroll
      for (int q=0;q<10;q++) gload16(gptr[q] + ko, &lds[cur^1][ldsOff[q]]);
    }
    const unsigned short* L = lds[cur];
    s16x8 ah[4], al[4], bh[6], bl[6];
    #pragma unroll
    for (int fm=0;fm<4;fm++){
      ah[fm] = *(const s16x8*)(L + aoff[fm]);
      al[fm] = *(const s16x8*)(L + aoff[fm] + 4096);
    }
    #pragma unroll
    for (int fn=0;fn<6;fn++){
      bh[fn] = *(const s16x8*)(L + boff[fn]);
      bl[fn] = *(const s16x8*)(L + boff[fn] + 6144);
    }
    #pragma unroll
    for (int fm=0;fm<4;fm++)
      #pragma unroll
      for (int fn=0;fn<6;fn++){
        acc[fm][fn] = __builtin_amdgcn_mfma_f32_16x16x32_bf16(ah[fm], bh[fn], acc[fm][fn], 0,0,0);
        acc[fm][fn] = __builtin_amdgcn_mfma_f32_16x16x32_bf16(ah[fm], bl[fn], acc[fm][fn], 0,0,0);
        acc[fm][fn] = __builtin_amdgcn_mfma_f32_16x16x32_bf16(al[fm], bh[fn], acc[fm][fn], 0,0,0);
      }
    cur ^= 1;
  }

  // epilogue: C/D layout col=lane&15, row=(lane>>4)*4+reg (m89/m91)
  int rl = (lane>>4)*4, cl = lane&15;
  float* outp = xw + (size_t)zz*XWHALF;
  #pragma unroll
  for (int fm=0;fm<4;fm++){
    #pragma unroll
    for (int fn=0;fn<6;fn++){
      int gr0 = mblk*128 + wm*64 + fm*16 + rl;
      int gc  = colBase + wn*96 + fn*16 + cl;
      f32x4 v = acc[fm][fn];
      #pragma unroll
      for (int r=0;r<4;r++){
        int gr = gr0 + r;
        if (gr < nrows)
          outp[(size_t)(chunkRow0 + gr)*G4 + gc] = v[r];
      }
    }
  }
}

// ---------------- LSTM: sums both K-half partials + bias --------------------
__global__ __launch_bounds__(384) void kLstm(const float* xw, const float* whh,
                                             const float* bih, const float* bhh, float* hsum){
  int b = blockIdx.x;
  int g = threadIdx.x;           // 0..383
  __shared__ __align__(16) float h_s[96];
  __shared__ float gbuf[384];
  float wreg[96];
  #pragma unroll
  for (int k=0;k<96;k++) wreg[k] = whh[(size_t)g*96 + k];
  float breg = bih[g] + bhh[g];
  float cval = 0.f, hacc = 0.f;
  if (g < 96) h_s[g] = 0.f;
  __syncthreads();
  const float* xrow  = xw + (size_t)b*50*G4;
  const float* xrow2 = xrow + XWHALF;
  for (int t=0;t<50;t++){
    float acc = xrow[t*G4 + g] + xrow2[t*G4 + g] + breg;
    #pragma unroll
    for (int k=0;k<96;k+=4){
      float4 h4 = *(const float4*)&h_s[k];
      acc += wreg[k]*h4.x + wreg[k+1]*h4.y + wreg[k+2]*h4.z + wreg[k+3]*h4.w;
    }
    gbuf[g] = acc;
    __syncthreads();
    if (g < 96){
      float ig = gbuf[g], fg = gbuf[96+g], gg = gbuf[192+g], og = gbuf[288+g];
      float si = 1.f/(1.f+expf(-ig));
      float sf = 1.f/(1.f+expf(-fg));
      float so = 1.f/(1.f+expf(-og));
      cval = sf*cval + si*tanhf(gg);
      float h = so * tanhf(cval);
      h_s[g] = h;
      hacc += h;
    }
    __syncthreads();
  }
  if (g < 96) hsum[(size_t)b*96 + g] = hacc;
}

// ---------------- head ------------------------------------------------------
__global__ void kOut(const float* hsum, const float* wfc, const float* bfc, float* out){
  int n = blockIdx.x;
  __shared__ float pool[96];
  int tid = threadIdx.x;   // 128
  if (tid < 96){
    float a = 0.f;
    for (int mv=0; mv<50; mv++) a += hsum[((size_t)(n*50 + mv))*96 + tid];
    pool[tid] = a / 2500.f;
  }
  __syncthreads();
  if (tid < 60){
    float a = bfc[tid];
    for (int o=0;o<96;o++) a += pool[o]*wfc[tid*96+o];
    out[n*60+tid] = a;
  }
}

extern "C" void kernel_launch(void* const* d_in, const int* in_sizes, int n_in,
                              void* d_out, int out_size, void* d_ws, size_t ws_size,
                              hipStream_t stream){
  const float* x     = (const float*)d_in[0];
  const float* bn_g  = (const float*)d_in[1];
  const float* bn_b  = (const float*)d_in[2];
  const float* bn_m  = (const float*)d_in[3];
  const float* bn_v  = (const float*)d_in[4];
  const float* Ap    = (const float*)d_in[5];
  const float* Ar    = (const float*)d_in[6];
  const float* Wg    = (const float*)d_in[7];
  const float* bg    = (const float*)d_in[8];
  const float* bn2_g = (const float*)d_in[9];
  const float* bn2_b = (const float*)d_in[10];
  const float* bn2_m = (const float*)d_in[11];
  const float* bn2_v = (const float*)d_in[12];
  const float* wih   = (const float*)d_in[13];
  const float* whh   = (const float*)d_in[14];
  const float* bih   = (const float*)d_in[15];
  const float* bhh   = (const float*)d_in[16];
  const float* wfc   = (const float*)d_in[17];
  const float* bfc   = (const float*)d_in[18];
  float* out = (float*)d_out;

  float* ws    = (float*)d_ws;
  float* geffT = ws;                        // 360,000
  float* beffT = geffT + 360000;            // 4,800
  int*   pairs = (int*)(beffT + 4800);      // 4,560
  float* pbuf  = beffT + 4800 + 4560;       // 5,760,000
  float* xw    = pbuf + 5760000;            // 7,680,000 (two K-half partials)
  float* hsum  = xw + 2*XWHALF;             // 19,200
  unsigned short* whiP = (unsigned short*)(hsum + 19200);   // 384*4768 shorts
  unsigned short* wloP = whiP + (size_t)G4*KP;
  unsigned short* fhi  = wloP + (size_t)G4*KP;              // chunkRows*KP shorts
  // fixed floats so far:
  size_t fixedFloats = 360000u + 4800u + 4560u + 5760000u + 2u*XWHALF + 19200u
                     + (size_t)G4*KP;       // W hi+lo = 2*(G4*KP) shorts = G4*KP floats
  long long availB = (long long)ws_size - (long long)(fixedFloats*4);
  long long perBlk128 = 128LL*KP*2*2;       // hi+lo bf16 per 128 rows
  int blocks128 = (availB > 0) ? (int)(availB / perBlk128) : 1;
  if (blocks128 < 1)  blocks128 = 1;
  if (blocks128 > 79) blocks128 = 79;
  int chunkRows = blocks128 * 128;
  unsigned short* flo = fhi + (size_t)chunkRows*KP;

  kGeff<<<(2*96*25*75 + 255)/256, 256, 0, stream>>>(bn_g, bn_v, Ap, Ar, Wg, bn2_g, bn2_v, geffT);
  kBeff<<<1200, 256, 0, stream>>>(bn_g, bn_b, bn_m, bn_v, Ap, Ar, Wg, bg,
                                  bn2_g, bn2_b, bn2_m, bn2_v, beffT);
  kPairs<<<(NPAIR + 255)/256, 256, 0, stream>>>(pairs);
  kWsplit<<<((G4*KP) + 255)/256, 256, 0, stream>>>(wih, whiP, wloP);
  kP<<<dim3(30, 8), 256, 0, stream>>>(x, geffT, beffT, pbuf);

  for (int r0 = 0; r0 < 10000; r0 += chunkRows){
    int nr = 10000 - r0; if (nr > chunkRows) nr = chunkRows;
    kFeat<<<nr, 256, 0, stream>>>(pbuf, pairs, fhi, flo, r0);
    kGemm<<<dim3(2, 2, (nr + 127)/128), 256, 0, stream>>>(fhi, flo, whiP, wloP, xw, r0, nr);
  }

  kLstm<<<200, 384, 0, stream>>>(xw, whh, bih, bhh, hsum);
  kOut<<<4, 128, 0, stream>>>(hsum, wfc, bfc, out);
}